// Round 9
// baseline (29.366 us; speedup 1.0000x reference)
//
#include <hip/hip_runtime.h>
#include <math.h>

#define B_    256
#define K_    5
#define N_    4096
#define NPAIR (B_ * K_)     // 1280
#define NACC  69            // 4 shared Q-moments + 5 * 13 per-k moments

// ---------------------------------------------------------------------------
// f32 3x3 eigensolve helpers (validated end-to-end: absmax 0.0 in R6-R8).
// ---------------------------------------------------------------------------
__device__ inline void cross3f(const float* a, const float* b, float* c) {
  c[0] = a[1] * b[2] - a[2] * b[1];
  c[1] = a[2] * b[0] - a[0] * b[2];
  c[2] = a[0] * b[1] - a[1] * b[0];
}
__device__ inline float dot3f(const float* a, const float* b) {
  return a[0] * b[0] + a[1] * b[1] + a[2] * b[2];
}
__device__ inline void fixsign3f(float* v) {
  const float a0 = fabsf(v[0]), a1 = fabsf(v[1]), a2 = fabsf(v[2]);
  const int i = (a0 >= a1 && a0 >= a2) ? 0 : ((a1 >= a2) ? 1 : 2);
  if (v[i] < 0.f) { v[0] = -v[0]; v[1] = -v[1]; v[2] = -v[2]; }
}
__device__ inline void eigvec3f(const float A[3][3], float lam, float* v) {
  const float r0[3] = {A[0][0] - lam, A[0][1], A[0][2]};
  const float r1[3] = {A[1][0], A[1][1] - lam, A[1][2]};
  const float r2[3] = {A[2][0], A[2][1], A[2][2] - lam};
  float c01[3], c02[3], c12[3];
  cross3f(r0, r1, c01); cross3f(r0, r2, c02); cross3f(r1, r2, c12);
  const float n01 = dot3f(c01, c01), n02 = dot3f(c02, c02), n12 = dot3f(c12, c12);
  const float* best = c01; float nb = n01;
  if (n02 > nb) { best = c02; nb = n02; }
  if (n12 > nb) { best = c12; nb = n12; }
  if (nb < 1e-30f) { v[0] = 1.f; v[1] = 0.f; v[2] = 0.f; return; }
  const float inv = 1.f / sqrtf(nb);
  v[0] = best[0] * inv; v[1] = best[1] * inv; v[2] = best[2] * inv;
}

// Reproduces the reference's buggy R = Vh diag(1,1,d) U^T via
//   tr(H R) = S0*M00 + S1*M11 + d*S2*M22,  M = Vh*Vh, d = sign(det H).
__device__ inline float svd_rmsd(const float* m) {
  const float invN = 1.f / (float)N_;
  const float sP[3] = {m[0], m[1], m[2]};
  const float sQ[3] = {m[3], m[4], m[5]};
  float H[3][3];
#pragma unroll
  for (int i = 0; i < 3; ++i)
#pragma unroll
    for (int j = 0; j < 3; ++j)
      H[i][j] = m[8 + 3 * i + j] - sP[i] * sQ[j] * invN;

  const float Sp = m[6] - dot3f(sP, sP) * invN;
  const float Sq = m[7] - dot3f(sQ, sQ) * invN;

  // A = H^T H (symmetric PSD)
  float A[3][3];
#pragma unroll
  for (int i = 0; i < 3; ++i)
#pragma unroll
    for (int j = 0; j < 3; ++j)
      A[i][j] = H[0][i] * H[0][j] + H[1][i] * H[1][j] + H[2][i] * H[2][j];

  float lam[3];
  float V[3][3];  // columns = eigenvectors
  const float q = (A[0][0] + A[1][1] + A[2][2]) * (1.f / 3.f);
  const float p1 = A[0][1] * A[0][1] + A[0][2] * A[0][2] + A[1][2] * A[1][2];
  const float p2 = (A[0][0] - q) * (A[0][0] - q) +
                   (A[1][1] - q) * (A[1][1] - q) +
                   (A[2][2] - q) * (A[2][2] - q) + 2.f * p1;
  if (p2 < 1e-20f) {
    lam[0] = lam[1] = lam[2] = q;
#pragma unroll
    for (int i = 0; i < 3; ++i)
#pragma unroll
      for (int j = 0; j < 3; ++j) V[i][j] = (i == j) ? 1.f : 0.f;
  } else {
    const float p = sqrtf(p2 * (1.f / 6.f));
    const float invp = 1.f / p;
    float Bm[3][3];
#pragma unroll
    for (int i = 0; i < 3; ++i)
#pragma unroll
      for (int j = 0; j < 3; ++j)
        Bm[i][j] = (A[i][j] - ((i == j) ? q : 0.f)) * invp;
    const float detB =
        Bm[0][0] * (Bm[1][1] * Bm[2][2] - Bm[1][2] * Bm[2][1]) -
        Bm[0][1] * (Bm[1][0] * Bm[2][2] - Bm[1][2] * Bm[2][0]) +
        Bm[0][2] * (Bm[1][0] * Bm[2][1] - Bm[1][1] * Bm[2][0]);
    float r = detB * 0.5f;
    r = fminf(1.f, fmaxf(-1.f, r));
    const float phi = acosf(r) * (1.f / 3.f);
    lam[0] = q + 2.f * p * cosf(phi);
    lam[2] = q + 2.f * p * cosf(phi + 2.0943951023931953f);  // +2pi/3
    lam[1] = 3.f * q - lam[0] - lam[2];

    float v1[3], v2[3], v3[3];
    eigvec3f(A, lam[0], v1);
    eigvec3f(A, lam[1], v2);
    // orthogonalize v2 against v1
    const float d12 = dot3f(v1, v2);
    v2[0] -= d12 * v1[0]; v2[1] -= d12 * v1[1]; v2[2] -= d12 * v1[2];
    float n2 = dot3f(v2, v2);
    if (n2 < 1e-12f) {
      const float a0 = fabsf(v1[0]), a1f = fabsf(v1[1]), a2f = fabsf(v1[2]);
      int ax = (a0 <= a1f && a0 <= a2f) ? 0 : ((a1f <= a2f) ? 1 : 2);
      float e[3] = {0.f, 0.f, 0.f};
      e[ax] = 1.f;
      const float de = dot3f(v1, e);
      v2[0] = e[0] - de * v1[0]; v2[1] = e[1] - de * v1[1]; v2[2] = e[2] - de * v1[2];
      n2 = dot3f(v2, v2);
    }
    const float invn2 = 1.f / sqrtf(n2);
    v2[0] *= invn2; v2[1] *= invn2; v2[2] *= invn2;

    fixsign3f(v1);
    fixsign3f(v2);
    cross3f(v1, v2, v3);
#pragma unroll
    for (int i = 0; i < 3; ++i) { V[i][0] = v1[i]; V[i][1] = v2[i]; V[i][2] = v3[i]; }
  }

  const float S0 = sqrtf(fmaxf(lam[0], 0.f));
  const float S1 = sqrtf(fmaxf(lam[1], 0.f));
  const float S2 = sqrtf(fmaxf(lam[2], 0.f));

  const float detH =
      H[0][0] * (H[1][1] * H[2][2] - H[1][2] * H[2][1]) -
      H[0][1] * (H[1][0] * H[2][2] - H[1][2] * H[2][0]) +
      H[0][2] * (H[1][0] * H[2][1] - H[1][1] * H[2][0]);
  const float dsg = (detH >= 0.f) ? 1.f : -1.f;

  // M = Vh*Vh (Vh = V^T): M_ii = sum_k V[k][i] * V[i][k]
  const float M00 = V[0][0] * V[0][0] + V[1][0] * V[0][1] + V[2][0] * V[0][2];
  const float M11 = V[0][1] * V[1][0] + V[1][1] * V[1][1] + V[2][1] * V[1][2];
  const float M22 = V[0][2] * V[2][0] + V[1][2] * V[2][1] + V[2][2] * V[2][2];

  const float T = S0 * M00 + S1 * M11 + dsg * S2 * M22;
  const float mse = (Sp + Sq - 2.f * T) * (1.f / (3.f * (float)N_));
  return sqrtf(mse + 1e-8f);
}

// ---------------------------------------------------------------------------
// Kernel 1: one block per b (grid=256, 512 threads). Each thread reads its Q
// chunk ONCE and the five P_k chunks, accumulating 5 moment sets (69 accums:
// [0..3] = sumQ,|q|^2 shared; [4+13k .. 16+13k] = sumP,|p|^2,H per k).
// Apparent vector-memory traffic drops 125.8 -> 75.5 MB (target read once) --
// R8 showed the kernel is pinned at the per-CU L1/TA delivery ceiling, so
// apparent bytes, not HBM bytes, set the floor. Tail: 8-wave butterfly +
// LDS cross-wave sum, then lanes 0-4 run the 5 f32 eigensolves in parallel.
// No cross-block sync (R4/R6 lesson). rmsd layout idx = k*256 + b.
// ---------------------------------------------------------------------------
__global__ __launch_bounds__(512) void kabsch_moments_svd(
    const float* __restrict__ preds, const float* __restrict__ target,
    float* __restrict__ rmsd) {
  const int b = blockIdx.x;           // 0..255
  const int tid = threadIdx.x;        // 0..511

  const float4* __restrict__ Q4 =
      reinterpret_cast<const float4*>(target) + (size_t)b * (N_ * 3 / 4);
  const float4* __restrict__ P4 =
      reinterpret_cast<const float4*>(preds) +
      (size_t)b * K_ * (N_ * 3 / 4);   // k stream at +k*3072 float4

  float acc[NACC];
#pragma unroll
  for (int i = 0; i < NACC; ++i) acc[i] = 0.f;

  // 4096 points = 1024 chunks of 4 points; 512 threads x 2 iterations.
#pragma unroll
  for (int it = 0; it < 2; ++it) {
    const int c = tid + it * 512;

    // issue all 18 float4 loads up front (independent streams, __restrict__)
    const float4 q0 = Q4[3 * c + 0], q1 = Q4[3 * c + 1], q2 = Q4[3 * c + 2];
    float4 pA[5], pB[5], pC[5];
#pragma unroll
    for (int k = 0; k < K_; ++k) {
      const float4* Pk = P4 + (size_t)k * (N_ * 3 / 4);
      pA[k] = Pk[3 * c + 0]; pB[k] = Pk[3 * c + 1]; pC[k] = Pk[3 * c + 2];
    }

    const float qq[4][3] = {{q0.x, q0.y, q0.z},
                            {q0.w, q1.x, q1.y},
                            {q1.z, q1.w, q2.x},
                            {q2.y, q2.z, q2.w}};
    // shared Q moments
#pragma unroll
    for (int m = 0; m < 4; ++m) {
      const float qx = qq[m][0], qy = qq[m][1], qz = qq[m][2];
      acc[0] += qx; acc[1] += qy; acc[2] += qz;
      acc[3] = fmaf(qx, qx, fmaf(qy, qy, fmaf(qz, qz, acc[3])));
    }
    // per-k moments
#pragma unroll
    for (int k = 0; k < K_; ++k) {
      const float pp[4][3] = {{pA[k].x, pA[k].y, pA[k].z},
                              {pA[k].w, pB[k].x, pB[k].y},
                              {pB[k].z, pB[k].w, pC[k].x},
                              {pC[k].y, pC[k].z, pC[k].w}};
      const int o = 4 + 13 * k;
#pragma unroll
      for (int m = 0; m < 4; ++m) {
        const float px = pp[m][0], py = pp[m][1], pz = pp[m][2];
        const float qx = qq[m][0], qy = qq[m][1], qz = qq[m][2];
        acc[o + 0] += px; acc[o + 1] += py; acc[o + 2] += pz;
        acc[o + 3] = fmaf(px, px, fmaf(py, py, fmaf(pz, pz, acc[o + 3])));
        acc[o + 4]  = fmaf(px, qx, acc[o + 4]);
        acc[o + 5]  = fmaf(px, qy, acc[o + 5]);
        acc[o + 6]  = fmaf(px, qz, acc[o + 6]);
        acc[o + 7]  = fmaf(py, qx, acc[o + 7]);
        acc[o + 8]  = fmaf(py, qy, acc[o + 8]);
        acc[o + 9]  = fmaf(py, qz, acc[o + 9]);
        acc[o + 10] = fmaf(pz, qx, acc[o + 10]);
        acc[o + 11] = fmaf(pz, qy, acc[o + 11]);
        acc[o + 12] = fmaf(pz, qz, acc[o + 12]);
      }
    }
  }

  // wave64 butterfly reduce all 69, then cross-wave via LDS
#pragma unroll
  for (int off = 32; off > 0; off >>= 1) {
#pragma unroll
    for (int i = 0; i < NACC; ++i) acc[i] += __shfl_down(acc[i], off, 64);
  }

  __shared__ float red[8][NACC];
  __shared__ float fin[NACC];
  const int lane = tid & 63, wid = tid >> 6;
  if (lane == 0) {
#pragma unroll
    for (int i = 0; i < NACC; ++i) red[wid][i] = acc[i];
  }
  __syncthreads();
  if (tid < NACC) {
    float s = 0.f;
#pragma unroll
    for (int w = 0; w < 8; ++w) s += red[w][tid];
    fin[tid] = s;
  }
  __syncthreads();

  // lanes 0..4 run the 5 eigensolves in parallel (same code path, SIMT)
  if (tid < K_) {
    const int o = 4 + 13 * tid;
    float m[17];
    m[0] = fin[o + 0]; m[1] = fin[o + 1]; m[2] = fin[o + 2];  // sumP
    m[3] = fin[0];     m[4] = fin[1];     m[5] = fin[2];      // sumQ
    m[6] = fin[o + 3];                                        // sum|p|^2
    m[7] = fin[3];                                            // sum|q|^2
#pragma unroll
    for (int i = 0; i < 9; ++i) m[8 + i] = fin[o + 4 + i];    // H
    rmsd[tid * 256 + b] = svd_rmsd(m);
  }
}

// ---------------------------------------------------------------------------
// Kernel 2: min over K, mean over B -> scalar.
// rmsd layout is idx = k*256 + b, so per-b min reads stride-256 (coalesced).
// ---------------------------------------------------------------------------
__global__ __launch_bounds__(256) void kabsch_final(
    const float* __restrict__ rmsd, float* __restrict__ out) {
  const int b = threadIdx.x;  // 256 threads == B_
  float mn = rmsd[b];
#pragma unroll
  for (int k = 1; k < K_; ++k) mn = fminf(mn, rmsd[k * 256 + b]);
#pragma unroll
  for (int off = 32; off > 0; off >>= 1) mn += __shfl_down(mn, off, 64);
  __shared__ float s[4];
  if ((b & 63) == 0) s[b >> 6] = mn;
  __syncthreads();
  if (b == 0) out[0] = (s[0] + s[1] + s[2] + s[3]) * (1.0f / 256.0f);
}

extern "C" void kernel_launch(void* const* d_in, const int* in_sizes, int n_in,
                              void* d_out, int out_size, void* d_ws, size_t ws_size,
                              hipStream_t stream) {
  const float* preds = (const float*)d_in[0];
  const float* target = (const float*)d_in[1];
  float* out = (float*)d_out;
  float* rm = (float*)d_ws;                      // NPAIR floats

  hipLaunchKernelGGL(kabsch_moments_svd, dim3(B_), dim3(512), 0, stream,
                     preds, target, rm);
  hipLaunchKernelGGL(kabsch_final, dim3(1), dim3(256), 0, stream, rm, out);
}

// Round 10
// 29.235 us; speedup vs baseline: 1.0045x; 1.0045x over previous
//
#include <hip/hip_runtime.h>
#include <math.h>

#define B_    256
#define K_    5
#define N_    4096
#define NPAIR (B_ * K_)     // 1280
#define NACC  69            // 4 shared Q-moments + 5 * 13 per-k moments

// ---------------------------------------------------------------------------
// f32 3x3 eigensolve helpers (validated end-to-end: absmax 0.0 in R6-R8).
// ---------------------------------------------------------------------------
__device__ inline void cross3f(const float* a, const float* b, float* c) {
  c[0] = a[1] * b[2] - a[2] * b[1];
  c[1] = a[2] * b[0] - a[0] * b[2];
  c[2] = a[0] * b[1] - a[1] * b[0];
}
__device__ inline float dot3f(const float* a, const float* b) {
  return a[0] * b[0] + a[1] * b[1] + a[2] * b[2];
}
__device__ inline void fixsign3f(float* v) {
  const float a0 = fabsf(v[0]), a1 = fabsf(v[1]), a2 = fabsf(v[2]);
  const int i = (a0 >= a1 && a0 >= a2) ? 0 : ((a1 >= a2) ? 1 : 2);
  if (v[i] < 0.f) { v[0] = -v[0]; v[1] = -v[1]; v[2] = -v[2]; }
}
__device__ inline void eigvec3f(const float A[3][3], float lam, float* v) {
  const float r0[3] = {A[0][0] - lam, A[0][1], A[0][2]};
  const float r1[3] = {A[1][0], A[1][1] - lam, A[1][2]};
  const float r2[3] = {A[2][0], A[2][1], A[2][2] - lam};
  float c01[3], c02[3], c12[3];
  cross3f(r0, r1, c01); cross3f(r0, r2, c02); cross3f(r1, r2, c12);
  const float n01 = dot3f(c01, c01), n02 = dot3f(c02, c02), n12 = dot3f(c12, c12);
  const float* best = c01; float nb = n01;
  if (n02 > nb) { best = c02; nb = n02; }
  if (n12 > nb) { best = c12; nb = n12; }
  if (nb < 1e-30f) { v[0] = 1.f; v[1] = 0.f; v[2] = 0.f; return; }
  const float inv = 1.f / sqrtf(nb);
  v[0] = best[0] * inv; v[1] = best[1] * inv; v[2] = best[2] * inv;
}

// Reproduces the reference's buggy R = Vh diag(1,1,d) U^T via
//   tr(H R) = S0*M00 + S1*M11 + d*S2*M22,  M = Vh*Vh, d = sign(det H).
__device__ inline float svd_rmsd(const float* m) {
  const float invN = 1.f / (float)N_;
  const float sP[3] = {m[0], m[1], m[2]};
  const float sQ[3] = {m[3], m[4], m[5]};
  float H[3][3];
#pragma unroll
  for (int i = 0; i < 3; ++i)
#pragma unroll
    for (int j = 0; j < 3; ++j)
      H[i][j] = m[8 + 3 * i + j] - sP[i] * sQ[j] * invN;

  const float Sp = m[6] - dot3f(sP, sP) * invN;
  const float Sq = m[7] - dot3f(sQ, sQ) * invN;

  // A = H^T H (symmetric PSD)
  float A[3][3];
#pragma unroll
  for (int i = 0; i < 3; ++i)
#pragma unroll
    for (int j = 0; j < 3; ++j)
      A[i][j] = H[0][i] * H[0][j] + H[1][i] * H[1][j] + H[2][i] * H[2][j];

  float lam[3];
  float V[3][3];  // columns = eigenvectors
  const float q = (A[0][0] + A[1][1] + A[2][2]) * (1.f / 3.f);
  const float p1 = A[0][1] * A[0][1] + A[0][2] * A[0][2] + A[1][2] * A[1][2];
  const float p2 = (A[0][0] - q) * (A[0][0] - q) +
                   (A[1][1] - q) * (A[1][1] - q) +
                   (A[2][2] - q) * (A[2][2] - q) + 2.f * p1;
  if (p2 < 1e-20f) {
    lam[0] = lam[1] = lam[2] = q;
#pragma unroll
    for (int i = 0; i < 3; ++i)
#pragma unroll
      for (int j = 0; j < 3; ++j) V[i][j] = (i == j) ? 1.f : 0.f;
  } else {
    const float p = sqrtf(p2 * (1.f / 6.f));
    const float invp = 1.f / p;
    float Bm[3][3];
#pragma unroll
    for (int i = 0; i < 3; ++i)
#pragma unroll
      for (int j = 0; j < 3; ++j)
        Bm[i][j] = (A[i][j] - ((i == j) ? q : 0.f)) * invp;
    const float detB =
        Bm[0][0] * (Bm[1][1] * Bm[2][2] - Bm[1][2] * Bm[2][1]) -
        Bm[0][1] * (Bm[1][0] * Bm[2][2] - Bm[1][2] * Bm[2][0]) +
        Bm[0][2] * (Bm[1][0] * Bm[2][1] - Bm[1][1] * Bm[2][0]);
    float r = detB * 0.5f;
    r = fminf(1.f, fmaxf(-1.f, r));
    const float phi = acosf(r) * (1.f / 3.f);
    lam[0] = q + 2.f * p * cosf(phi);
    lam[2] = q + 2.f * p * cosf(phi + 2.0943951023931953f);  // +2pi/3
    lam[1] = 3.f * q - lam[0] - lam[2];

    float v1[3], v2[3], v3[3];
    eigvec3f(A, lam[0], v1);
    eigvec3f(A, lam[1], v2);
    // orthogonalize v2 against v1
    const float d12 = dot3f(v1, v2);
    v2[0] -= d12 * v1[0]; v2[1] -= d12 * v1[1]; v2[2] -= d12 * v1[2];
    float n2 = dot3f(v2, v2);
    if (n2 < 1e-12f) {
      const float a0 = fabsf(v1[0]), a1f = fabsf(v1[1]), a2f = fabsf(v1[2]);
      int ax = (a0 <= a1f && a0 <= a2f) ? 0 : ((a1f <= a2f) ? 1 : 2);
      float e[3] = {0.f, 0.f, 0.f};
      e[ax] = 1.f;
      const float de = dot3f(v1, e);
      v2[0] = e[0] - de * v1[0]; v2[1] = e[1] - de * v1[1]; v2[2] = e[2] - de * v1[2];
      n2 = dot3f(v2, v2);
    }
    const float invn2 = 1.f / sqrtf(n2);
    v2[0] *= invn2; v2[1] *= invn2; v2[2] *= invn2;

    fixsign3f(v1);
    fixsign3f(v2);
    cross3f(v1, v2, v3);
#pragma unroll
    for (int i = 0; i < 3; ++i) { V[i][0] = v1[i]; V[i][1] = v2[i]; V[i][2] = v3[i]; }
  }

  const float S0 = sqrtf(fmaxf(lam[0], 0.f));
  const float S1 = sqrtf(fmaxf(lam[1], 0.f));
  const float S2 = sqrtf(fmaxf(lam[2], 0.f));

  const float detH =
      H[0][0] * (H[1][1] * H[2][2] - H[1][2] * H[2][1]) -
      H[0][1] * (H[1][0] * H[2][2] - H[1][2] * H[2][0]) +
      H[0][2] * (H[1][0] * H[2][1] - H[1][1] * H[2][0]);
  const float dsg = (detH >= 0.f) ? 1.f : -1.f;

  // M = Vh*Vh (Vh = V^T): M_ii = sum_k V[k][i] * V[i][k]
  const float M00 = V[0][0] * V[0][0] + V[1][0] * V[0][1] + V[2][0] * V[0][2];
  const float M11 = V[0][1] * V[1][0] + V[1][1] * V[1][1] + V[2][1] * V[1][2];
  const float M22 = V[0][2] * V[2][0] + V[1][2] * V[2][1] + V[2][2] * V[2][2];

  const float T = S0 * M00 + S1 * M11 + dsg * S2 * M22;
  const float mse = (Sp + Sq - 2.f * T) * (1.f / (3.f * (float)N_));
  return sqrtf(mse + 1e-8f);
}

// ---------------------------------------------------------------------------
// Kernel 1: one block per b (grid=256, 512 threads). Each thread reads its Q
// chunk ONCE and the five P_k chunks, accumulating 5 moment sets (69 accums:
// [0..3] = sumQ,|q|^2 shared; [4+13k .. 16+13k] = sumP,|p|^2,H per k).
// Apparent vector-memory traffic drops 125.8 -> 75.5 MB (target read once) --
// R8 showed the kernel is pinned at the per-CU L1/TA delivery ceiling, so
// apparent bytes, not HBM bytes, set the floor. Tail: 8-wave butterfly +
// LDS cross-wave sum, then lanes 0-4 run the 5 f32 eigensolves in parallel.
// No cross-block sync (R4/R6 lesson). rmsd layout idx = k*256 + b.
// ---------------------------------------------------------------------------
__global__ __launch_bounds__(512) void kabsch_moments_svd(
    const float* __restrict__ preds, const float* __restrict__ target,
    float* __restrict__ rmsd) {
  const int b = blockIdx.x;           // 0..255
  const int tid = threadIdx.x;        // 0..511

  const float4* __restrict__ Q4 =
      reinterpret_cast<const float4*>(target) + (size_t)b * (N_ * 3 / 4);
  const float4* __restrict__ P4 =
      reinterpret_cast<const float4*>(preds) +
      (size_t)b * K_ * (N_ * 3 / 4);   // k stream at +k*3072 float4

  float acc[NACC];
#pragma unroll
  for (int i = 0; i < NACC; ++i) acc[i] = 0.f;

  // 4096 points = 1024 chunks of 4 points; 512 threads x 2 iterations.
#pragma unroll
  for (int it = 0; it < 2; ++it) {
    const int c = tid + it * 512;

    // issue all 18 float4 loads up front (independent streams, __restrict__)
    const float4 q0 = Q4[3 * c + 0], q1 = Q4[3 * c + 1], q2 = Q4[3 * c + 2];
    float4 pA[5], pB[5], pC[5];
#pragma unroll
    for (int k = 0; k < K_; ++k) {
      const float4* Pk = P4 + (size_t)k * (N_ * 3 / 4);
      pA[k] = Pk[3 * c + 0]; pB[k] = Pk[3 * c + 1]; pC[k] = Pk[3 * c + 2];
    }

    const float qq[4][3] = {{q0.x, q0.y, q0.z},
                            {q0.w, q1.x, q1.y},
                            {q1.z, q1.w, q2.x},
                            {q2.y, q2.z, q2.w}};
    // shared Q moments
#pragma unroll
    for (int m = 0; m < 4; ++m) {
      const float qx = qq[m][0], qy = qq[m][1], qz = qq[m][2];
      acc[0] += qx; acc[1] += qy; acc[2] += qz;
      acc[3] = fmaf(qx, qx, fmaf(qy, qy, fmaf(qz, qz, acc[3])));
    }
    // per-k moments
#pragma unroll
    for (int k = 0; k < K_; ++k) {
      const float pp[4][3] = {{pA[k].x, pA[k].y, pA[k].z},
                              {pA[k].w, pB[k].x, pB[k].y},
                              {pB[k].z, pB[k].w, pC[k].x},
                              {pC[k].y, pC[k].z, pC[k].w}};
      const int o = 4 + 13 * k;
#pragma unroll
      for (int m = 0; m < 4; ++m) {
        const float px = pp[m][0], py = pp[m][1], pz = pp[m][2];
        const float qx = qq[m][0], qy = qq[m][1], qz = qq[m][2];
        acc[o + 0] += px; acc[o + 1] += py; acc[o + 2] += pz;
        acc[o + 3] = fmaf(px, px, fmaf(py, py, fmaf(pz, pz, acc[o + 3])));
        acc[o + 4]  = fmaf(px, qx, acc[o + 4]);
        acc[o + 5]  = fmaf(px, qy, acc[o + 5]);
        acc[o + 6]  = fmaf(px, qz, acc[o + 6]);
        acc[o + 7]  = fmaf(py, qx, acc[o + 7]);
        acc[o + 8]  = fmaf(py, qy, acc[o + 8]);
        acc[o + 9]  = fmaf(py, qz, acc[o + 9]);
        acc[o + 10] = fmaf(pz, qx, acc[o + 10]);
        acc[o + 11] = fmaf(pz, qy, acc[o + 11]);
        acc[o + 12] = fmaf(pz, qz, acc[o + 12]);
      }
    }
  }

  // wave64 butterfly reduce all 69, then cross-wave via LDS
#pragma unroll
  for (int off = 32; off > 0; off >>= 1) {
#pragma unroll
    for (int i = 0; i < NACC; ++i) acc[i] += __shfl_down(acc[i], off, 64);
  }

  __shared__ float red[8][NACC];
  __shared__ float fin[NACC];
  const int lane = tid & 63, wid = tid >> 6;
  if (lane == 0) {
#pragma unroll
    for (int i = 0; i < NACC; ++i) red[wid][i] = acc[i];
  }
  __syncthreads();
  if (tid < NACC) {
    float s = 0.f;
#pragma unroll
    for (int w = 0; w < 8; ++w) s += red[w][tid];
    fin[tid] = s;
  }
  __syncthreads();

  // lanes 0..4 run the 5 eigensolves in parallel (same code path, SIMT)
  if (tid < K_) {
    const int o = 4 + 13 * tid;
    float m[17];
    m[0] = fin[o + 0]; m[1] = fin[o + 1]; m[2] = fin[o + 2];  // sumP
    m[3] = fin[0];     m[4] = fin[1];     m[5] = fin[2];      // sumQ
    m[6] = fin[o + 3];                                        // sum|p|^2
    m[7] = fin[3];                                            // sum|q|^2
#pragma unroll
    for (int i = 0; i < 9; ++i) m[8 + i] = fin[o + 4 + i];    // H
    rmsd[tid * 256 + b] = svd_rmsd(m);
  }
}

// ---------------------------------------------------------------------------
// Kernel 2: min over K, mean over B -> scalar.
// rmsd layout is idx = k*256 + b, so per-b min reads stride-256 (coalesced).
// ---------------------------------------------------------------------------
__global__ __launch_bounds__(256) void kabsch_final(
    const float* __restrict__ rmsd, float* __restrict__ out) {
  const int b = threadIdx.x;  // 256 threads == B_
  float mn = rmsd[b];
#pragma unroll
  for (int k = 1; k < K_; ++k) mn = fminf(mn, rmsd[k * 256 + b]);
#pragma unroll
  for (int off = 32; off > 0; off >>= 1) mn += __shfl_down(mn, off, 64);
  __shared__ float s[4];
  if ((b & 63) == 0) s[b >> 6] = mn;
  __syncthreads();
  if (b == 0) out[0] = (s[0] + s[1] + s[2] + s[3]) * (1.0f / 256.0f);
}

extern "C" void kernel_launch(void* const* d_in, const int* in_sizes, int n_in,
                              void* d_out, int out_size, void* d_ws, size_t ws_size,
                              hipStream_t stream) {
  const float* preds = (const float*)d_in[0];
  const float* target = (const float*)d_in[1];
  float* out = (float*)d_out;
  float* rm = (float*)d_ws;                      // NPAIR floats

  hipLaunchKernelGGL(kabsch_moments_svd, dim3(B_), dim3(512), 0, stream,
                     preds, target, rm);
  hipLaunchKernelGGL(kabsch_final, dim3(1), dim3(256), 0, stream, rm, out);
}